// Round 3
// baseline (302.738 us; speedup 1.0000x reference)
//
#include <hip/hip_runtime.h>
#include <hip/hip_fp16.h>

// Problem constants (match reference setup_inputs()).
constexpr int B = 4, C = 8, H = 160, W = 160, Dd = 160, NPER = 100000;
constexpr long HWD = (long)H * W * Dd;            // 4,096,000 voxels per image
constexpr int  TOTAL_PTS = NPER * B;              // 400,000 (point, image) pairs
constexpr int  TOTAL_OUT = NPER * B * C;          // 3,200,000 output elements
constexpr int  NKEYS = B * H * W;                 // 102,400 (b, x1, y1) buckets

// Workspace layout (bytes); all offsets 256-aligned.
constexpr size_t WS_IMG_BYTES    = (size_t)B * HWD * C * sizeof(__half); // 262,144,000
constexpr size_t WS_COUNTS_OFF   = WS_IMG_BYTES;                         // 102,400 * 4
constexpr size_t WS_SORTED_OFF   = WS_COUNTS_OFF + (size_t)NKEYS * 4;    // 400,000 * 4
constexpr size_t WS_NEEDED       = WS_SORTED_OFF + (size_t)TOTAL_PTS * 4;

__device__ __forceinline__ float load_image_dim(const int* dimp) {
    int iv = dimp[0];
    return (iv > 0 && iv < 1000000) ? (float)iv : __int_as_float(iv);
}

// Shared coordinate math (must be identical in hist/scatter/gather).
struct Coord {
    int x1, x2, y1, y2, z1, z2;
    float wx, wx2, wy, wy2, wz, wz2;
};
__device__ __forceinline__ Coord make_coord(const float* __restrict__ gf,
                                            int p, float factor) {
    Coord c;
    float x = gf[(long)p * 3 + 0] / factor;
    float y = gf[(long)p * 3 + 1] / factor;
    float z = gf[(long)p * 3 + 2] / factor;
    float x1f = fminf(floorf(x), (float)(H - 1));
    float x2f = fminf(ceilf(x),  (float)(H - 1));
    float y1f = fminf(floorf(y), (float)(W - 1));
    float y2f = fminf(ceilf(y),  (float)(W - 1));
    float z1f = fminf(floorf(z), (float)(Dd - 1));
    float z2f = fminf(ceilf(z),  (float)(Dd - 1));
    c.x1 = max(0, (int)x1f); c.x2 = max(0, (int)x2f);
    c.y1 = max(0, (int)y1f); c.y2 = max(0, (int)y2f);
    c.z1 = max(0, (int)z1f); c.z2 = max(0, (int)z2f);
    c.wx = x - x1f; c.wx2 = x2f - x;
    c.wy = y - y1f; c.wy2 = y2f - y;
    c.wz = z - z1f; c.wz2 = z2f - z;
    return c;
}

// ---------------------------------------------------------------------------
// Sort pass 1: histogram of (b, x1, y1) keys.
// ---------------------------------------------------------------------------
__global__ __launch_bounds__(256) void hist_kernel(
    const float* __restrict__ gf, const int* __restrict__ dimp,
    int* __restrict__ counts)
{
    int p = blockIdx.x * 256 + threadIdx.x;
    if (p >= TOTAL_PTS) return;
    float factor = load_image_dim(dimp) / (float)H;
    int b = p / NPER;
    Coord c = make_coord(gf, p, factor);
    int key = (b * H + c.x1) * W + c.y1;
    atomicAdd(&counts[key], 1);
}

// ---------------------------------------------------------------------------
// Sort pass 2: exclusive prefix sum over 102,400 counts (single block).
// ---------------------------------------------------------------------------
__global__ __launch_bounds__(1024) void scan_kernel(int* __restrict__ counts)
{
    constexpr int CHUNK = NKEYS / 1024;   // 100
    __shared__ int part[1024];
    int tid = threadIdx.x;
    int beg = tid * CHUNK;
    int s = 0;
    #pragma unroll 4
    for (int i = 0; i < CHUNK; ++i) s += counts[beg + i];
    part[tid] = s;
    __syncthreads();
    // Hillis-Steele inclusive scan in LDS
    for (int off = 1; off < 1024; off <<= 1) {
        int v = (tid >= off) ? part[tid - off] : 0;
        __syncthreads();
        part[tid] += v;
        __syncthreads();
    }
    int run = part[tid] - s;              // exclusive prefix for this chunk
    for (int i = 0; i < CHUNK; ++i) {
        int cnt = counts[beg + i];
        counts[beg + i] = run;
        run += cnt;
    }
}

// ---------------------------------------------------------------------------
// Sort pass 3: scatter point ids into sorted order (mutates counts).
// ---------------------------------------------------------------------------
__global__ __launch_bounds__(256) void scatter_kernel(
    const float* __restrict__ gf, const int* __restrict__ dimp,
    int* __restrict__ counts, int* __restrict__ sorted)
{
    int p = blockIdx.x * 256 + threadIdx.x;
    if (p >= TOTAL_PTS) return;
    float factor = load_image_dim(dimp) / (float)H;
    int b = p / NPER;
    Coord c = make_coord(gf, p, factor);
    int key = (b * H + c.x1) * W + c.y1;
    int pos = atomicAdd(&counts[key], 1);
    sorted[pos] = p;
}

// ---------------------------------------------------------------------------
// Pass 4: [B,C,H,W,D] fp32 -> [B, H*W*D, C] fp16 channel-last, 4 voxels/thread.
// ---------------------------------------------------------------------------
__global__ __launch_bounds__(256) void transpose_kernel(
    const float* __restrict__ img, __half* __restrict__ ws)
{
    long t = (long)blockIdx.x * 256 + threadIdx.x;
    const long nquads = (long)B * HWD / 4;
    if (t >= nquads) return;
    long v0 = t * 4;
    long b  = v0 / HWD;
    long v  = v0 - b * HWD;
    const float* base = img + b * C * HWD + v;

    float4 ch[8];
    #pragma unroll
    for (int c = 0; c < 8; ++c)
        ch[c] = *reinterpret_cast<const float4*>(base + (long)c * HWD);

    #pragma unroll
    for (int q = 0; q < 4; ++q) {
        __half h[8];
        #pragma unroll
        for (int c = 0; c < 8; ++c)
            h[c] = __float2half(reinterpret_cast<const float*>(&ch[c])[q]);
        *reinterpret_cast<float4*>(ws + (v0 + q) * 8) =
            *reinterpret_cast<const float4*>(h);
    }
}

// ---------------------------------------------------------------------------
// Pass 5: gather in sorted order. 8 corners x 16 B fp16, exact reference lerp.
// ---------------------------------------------------------------------------
__global__ __launch_bounds__(256) void gather_kernel(
    const __half* __restrict__ ws, const float* __restrict__ gf,
    const int* __restrict__ dimp, const int* __restrict__ sorted,
    float* __restrict__ out)
{
    int i = blockIdx.x * 256 + threadIdx.x;
    if (i >= TOTAL_PTS) return;
    int p = sorted[i];
    int b = p / NPER;
    int j = p - b * NPER;

    float factor = load_image_dim(dimp) / (float)H;
    Coord cc = make_coord(gf, p, factor);

    const __half* base = ws + (long)b * HWD * 8;
    auto corner = [&](int xi, int yi, int zi, float* v) {
        long vox = ((long)xi * W + yi) * Dd + zi;
        float4 raw = *reinterpret_cast<const float4*>(base + vox * 8);
        const __half* h = reinterpret_cast<const __half*>(&raw);
        #pragma unroll
        for (int c = 0; c < 8; ++c) v[c] = __half2float(h[c]);
    };

    float a11[8], a12[8], a21[8], a22[8], ly_a[8], ly_b[8];

    corner(cc.x1, cc.y1, cc.z2, a11);
    corner(cc.x1, cc.y2, cc.z2, a12);
    corner(cc.x2, cc.y1, cc.z2, a21);
    corner(cc.x2, cc.y2, cc.z2, a22);
    #pragma unroll
    for (int c = 0; c < 8; ++c) {
        float lx1 = a21[c] * cc.wx + a11[c] * cc.wx2;
        float lx2 = a22[c] * cc.wx + a12[c] * cc.wx2;
        ly_a[c] = lx2 * cc.wy + lx1 * cc.wy2;
    }
    corner(cc.x1, cc.y1, cc.z1, a11);
    corner(cc.x1, cc.y2, cc.z1, a12);
    corner(cc.x2, cc.y1, cc.z1, a21);
    corner(cc.x2, cc.y2, cc.z1, a22);
    #pragma unroll
    for (int c = 0; c < 8; ++c) {
        float lx1 = a21[c] * cc.wx + a11[c] * cc.wx2;
        float lx2 = a22[c] * cc.wx + a12[c] * cc.wx2;
        ly_b[c] = lx2 * cc.wy + lx1 * cc.wy2;
    }

    float res[8];
    #pragma unroll
    for (int c = 0; c < 8; ++c) res[c] = ly_a[c] * cc.wz + ly_b[c] * cc.wz2;

    float* dst = out + (long)j * 32 + b * 8;
    *reinterpret_cast<float4*>(dst)     = *reinterpret_cast<const float4*>(&res[0]);
    *reinterpret_cast<float4*>(dst + 4) = *reinterpret_cast<const float4*>(&res[4]);
}

// ---------------------------------------------------------------------------
// Fallback: direct gather on original layout (round-1 kernel).
// ---------------------------------------------------------------------------
__global__ __launch_bounds__(256) void og_proj_direct(
    const float* __restrict__ img, const float* __restrict__ gf,
    const int* __restrict__ dimp, float* __restrict__ out)
{
    int o = blockIdx.x * 256 + threadIdx.x;
    if (o >= TOTAL_OUT) return;
    int j = o >> 5, bc = o & 31, b = bc >> 3, c = bc & 7;
    float factor = load_image_dim(dimp) / (float)H;
    Coord cc = make_coord(gf, b * NPER + j, factor);

    const float* base = img + (size_t)(b * C + c) * (size_t)HWD;
    size_t r11 = ((size_t)cc.x1 * W + cc.y1) * Dd;
    size_t r12 = ((size_t)cc.x1 * W + cc.y2) * Dd;
    size_t r21 = ((size_t)cc.x2 * W + cc.y1) * Dd;
    size_t r22 = ((size_t)cc.x2 * W + cc.y2) * Dd;

    float lx1_a = base[r21 + cc.z2] * cc.wx + base[r11 + cc.z2] * cc.wx2;
    float lx2_a = base[r22 + cc.z2] * cc.wx + base[r12 + cc.z2] * cc.wx2;
    float ly_a  = lx2_a * cc.wy + lx1_a * cc.wy2;
    float lx1_b = base[r21 + cc.z1] * cc.wx + base[r11 + cc.z1] * cc.wx2;
    float lx2_b = base[r22 + cc.z1] * cc.wx + base[r12 + cc.z1] * cc.wx2;
    float ly_b  = lx2_b * cc.wy + lx1_b * cc.wy2;
    out[o] = ly_a * cc.wz + ly_b * cc.wz2;
}

extern "C" void kernel_launch(void* const* d_in, const int* in_sizes, int n_in,
                              void* d_out, int out_size, void* d_ws, size_t ws_size,
                              hipStream_t stream) {
    const float* img  = (const float*)d_in[0];
    const float* gf   = (const float*)d_in[1];
    const int*   dimp = (const int*)d_in[3];
    float* out = (float*)d_out;

    if (ws_size >= WS_NEEDED) {
        __half* ws = (__half*)d_ws;
        int* counts = (int*)((char*)d_ws + WS_COUNTS_OFF);
        int* sorted = (int*)((char*)d_ws + WS_SORTED_OFF);

        // Sort points by (b, x1, y1) — counting sort, 3 tiny passes.
        hipMemsetAsync(counts, 0, (size_t)NKEYS * 4, stream);
        int pblocks = (TOTAL_PTS + 255) / 256;
        hist_kernel<<<pblocks, 256, 0, stream>>>(gf, dimp, counts);
        scan_kernel<<<1, 1024, 0, stream>>>(counts);
        scatter_kernel<<<pblocks, 256, 0, stream>>>(gf, dimp, counts, sorted);

        // Channel-last fp16 copy, then locality-friendly gather.
        long nquads = (long)B * HWD / 4;
        int tblocks = (int)((nquads + 255) / 256);
        transpose_kernel<<<tblocks, 256, 0, stream>>>(img, ws);
        gather_kernel<<<pblocks, 256, 0, stream>>>(ws, gf, dimp, sorted, out);
    } else {
        int blocks = (TOTAL_OUT + 255) / 256;
        og_proj_direct<<<blocks, 256, 0, stream>>>(img, gf, dimp, out);
    }
}

// Round 4
// 230.367 us; speedup vs baseline: 1.3142x; 1.3142x over previous
//
#include <hip/hip_runtime.h>
#include <hip/hip_fp16.h>

// Problem constants (match reference setup_inputs()).
constexpr int B = 4, C = 8, H = 160, W = 160, Dd = 160, NPER = 100000;
constexpr long HWD = (long)H * W * Dd;            // 4,096,000 voxels per image
constexpr int  TOTAL_PTS = NPER * B;              // 400,000 (point, image) pairs
constexpr int  TOTAL_OUT = NPER * B * C;          // 3,200,000 output elements
constexpr int  NKEYS = B * H * W;                 // 102,400 (b, x1, y1) buckets
constexpr int  SCAN_BLOCKS = NKEYS / 256;         // 400

typedef float  f32x4 __attribute__((ext_vector_type(4)));

// Workspace layout (bytes).
constexpr size_t WS_IMG_BYTES   = (size_t)B * HWD * C * sizeof(__half); // 262,144,000
constexpr size_t WS_COUNTS_OFF  = WS_IMG_BYTES;                          // NKEYS*4
constexpr size_t WS_PART_OFF    = WS_COUNTS_OFF + (size_t)NKEYS * 4;     // 400*4 (pad 256)
constexpr size_t WS_PAY_OFF     = WS_PART_OFF + 4096;
constexpr size_t WS_NEEDED      = WS_PAY_OFF + (size_t)TOTAL_PTS * 16;

__device__ __forceinline__ float load_image_dim(const int* dimp) {
    int iv = dimp[0];
    return (iv > 0 && iv < 1000000) ? (float)iv : __int_as_float(iv);
}

struct Coord {
    int x1, x2, y1, y2, z1, z2;
    float wx, wx2, wy, wy2, wz, wz2;
};
// Must be bit-identical everywhere it is used.
__device__ __forceinline__ Coord coord_from_xyz(float gx, float gy, float gz,
                                                float factor) {
    Coord c;
    float x = gx / factor, y = gy / factor, z = gz / factor;
    float x1f = fminf(floorf(x), (float)(H - 1));
    float x2f = fminf(ceilf(x),  (float)(H - 1));
    float y1f = fminf(floorf(y), (float)(W - 1));
    float y2f = fminf(ceilf(y),  (float)(W - 1));
    float z1f = fminf(floorf(z), (float)(Dd - 1));
    float z2f = fminf(ceilf(z),  (float)(Dd - 1));
    c.x1 = max(0, (int)x1f); c.x2 = max(0, (int)x2f);
    c.y1 = max(0, (int)y1f); c.y2 = max(0, (int)y2f);
    c.z1 = max(0, (int)z1f); c.z2 = max(0, (int)z2f);
    c.wx = x - x1f; c.wx2 = x2f - x;
    c.wy = y - y1f; c.wy2 = y2f - y;
    c.wz = z - z1f; c.wz2 = z2f - z;
    return c;
}

// --------------------------- sort machinery --------------------------------
__global__ __launch_bounds__(256) void zero_kernel(int* __restrict__ counts) {
    int i = blockIdx.x * 256 + threadIdx.x;
    if (i < NKEYS) counts[i] = 0;
}

__global__ __launch_bounds__(256) void hist_kernel(
    const float* __restrict__ gf, const int* __restrict__ dimp,
    int* __restrict__ counts)
{
    int p = blockIdx.x * 256 + threadIdx.x;
    if (p >= TOTAL_PTS) return;
    float factor = load_image_dim(dimp) / (float)H;
    int b = p / NPER;
    Coord c = coord_from_xyz(gf[(long)p*3], gf[(long)p*3+1], gf[(long)p*3+2], factor);
    atomicAdd(&counts[(b * H + c.x1) * W + c.y1], 1);
}

// Block-local exclusive scan; per-block totals to partials.
__global__ __launch_bounds__(256) void scanA_kernel(
    int* __restrict__ counts, int* __restrict__ partials)
{
    __shared__ int sm[256];
    int g = blockIdx.x * 256 + threadIdx.x;
    int v = counts[g];
    sm[threadIdx.x] = v;
    __syncthreads();
    for (int off = 1; off < 256; off <<= 1) {
        int t = (threadIdx.x >= off) ? sm[threadIdx.x - off] : 0;
        __syncthreads();
        sm[threadIdx.x] += t;
        __syncthreads();
    }
    counts[g] = sm[threadIdx.x] - v;                 // exclusive within block
    if (threadIdx.x == 255) partials[blockIdx.x] = sm[255];
}

// Exclusive scan of the 400 block totals (single small block — tiny).
__global__ __launch_bounds__(512) void scanB_kernel(int* __restrict__ partials)
{
    __shared__ int sm[512];
    int t = threadIdx.x;
    int v = (t < SCAN_BLOCKS) ? partials[t] : 0;
    sm[t] = v;
    __syncthreads();
    for (int off = 1; off < 512; off <<= 1) {
        int u = (t >= off) ? sm[t - off] : 0;
        __syncthreads();
        sm[t] += u;
        __syncthreads();
    }
    if (t < SCAN_BLOCKS) partials[t] = sm[t] - v;    // exclusive
}

__global__ __launch_bounds__(256) void scanC_kernel(
    int* __restrict__ counts, const int* __restrict__ partials)
{
    int g = blockIdx.x * 256 + threadIdx.x;
    counts[g] += partials[blockIdx.x];
}

// Scatter payload {p_bits, gx, gy, gz} into sorted position.
__global__ __launch_bounds__(256) void scatter_kernel(
    const float* __restrict__ gf, const int* __restrict__ dimp,
    int* __restrict__ counts, f32x4* __restrict__ payload)
{
    int p = blockIdx.x * 256 + threadIdx.x;
    if (p >= TOTAL_PTS) return;
    float factor = load_image_dim(dimp) / (float)H;
    int b = p / NPER;
    float gx = gf[(long)p*3], gy = gf[(long)p*3+1], gz = gf[(long)p*3+2];
    Coord c = coord_from_xyz(gx, gy, gz, factor);
    int pos = atomicAdd(&counts[(b * H + c.x1) * W + c.y1], 1);
    f32x4 rec;
    rec.x = __int_as_float(p); rec.y = gx; rec.z = gy; rec.w = gz;
    payload[pos] = rec;
}

// --------------------------- transpose -------------------------------------
// [B,C,H,W,D] fp32 -> [B, H*W*D, C] fp16, 4 voxels/thread.
// img reads are NON-TEMPORAL so the 512 MB stream does not evict the ws
// lines we are writing from L3 (ws = 262 MB ~ fits the 256 MiB LLC).
__global__ __launch_bounds__(256) void transpose_kernel(
    const float* __restrict__ img, __half* __restrict__ ws)
{
    long t = (long)blockIdx.x * 256 + threadIdx.x;
    const long nquads = (long)B * HWD / 4;
    if (t >= nquads) return;
    long v0 = t * 4;
    long b  = v0 / HWD;
    long v  = v0 - b * HWD;
    const float* base = img + b * C * HWD + v;

    f32x4 ch[8];
    #pragma unroll
    for (int c = 0; c < 8; ++c)
        ch[c] = __builtin_nontemporal_load(
            reinterpret_cast<const f32x4*>(base + (long)c * HWD));

    #pragma unroll
    for (int q = 0; q < 4; ++q) {
        __half h[8];
        #pragma unroll
        for (int c = 0; c < 8; ++c) h[c] = __float2half(ch[c][q]);
        *reinterpret_cast<f32x4*>(ws + (v0 + q) * 8) =
            *reinterpret_cast<const f32x4*>(h);
    }
}

// --------------------------- gather ----------------------------------------
__global__ __launch_bounds__(256) void gather_kernel(
    const __half* __restrict__ ws, const f32x4* __restrict__ payload,
    const int* __restrict__ dimp, float* __restrict__ out)
{
    int i = blockIdx.x * 256 + threadIdx.x;
    if (i >= TOTAL_PTS) return;
    f32x4 rec = payload[i];
    int p = __float_as_int(rec.x);
    int b = p / NPER;
    int j = p - b * NPER;

    float factor = load_image_dim(dimp) / (float)H;
    Coord cc = coord_from_xyz(rec.y, rec.z, rec.w, factor);

    const __half* base = ws + (long)b * HWD * 8;
    auto corner = [&](int xi, int yi, int zi, float* v) {
        long vox = ((long)xi * W + yi) * Dd + zi;
        f32x4 raw = *reinterpret_cast<const f32x4*>(base + vox * 8);
        const __half* h = reinterpret_cast<const __half*>(&raw);
        #pragma unroll
        for (int c = 0; c < 8; ++c) v[c] = __half2float(h[c]);
    };

    float a11[8], a12[8], a21[8], a22[8], ly_a[8], ly_b[8];

    corner(cc.x1, cc.y1, cc.z2, a11);
    corner(cc.x1, cc.y2, cc.z2, a12);
    corner(cc.x2, cc.y1, cc.z2, a21);
    corner(cc.x2, cc.y2, cc.z2, a22);
    #pragma unroll
    for (int c = 0; c < 8; ++c) {
        float lx1 = a21[c] * cc.wx + a11[c] * cc.wx2;
        float lx2 = a22[c] * cc.wx + a12[c] * cc.wx2;
        ly_a[c] = lx2 * cc.wy + lx1 * cc.wy2;
    }
    corner(cc.x1, cc.y1, cc.z1, a11);
    corner(cc.x1, cc.y2, cc.z1, a12);
    corner(cc.x2, cc.y1, cc.z1, a21);
    corner(cc.x2, cc.y2, cc.z1, a22);
    #pragma unroll
    for (int c = 0; c < 8; ++c) {
        float lx1 = a21[c] * cc.wx + a11[c] * cc.wx2;
        float lx2 = a22[c] * cc.wx + a12[c] * cc.wx2;
        ly_b[c] = lx2 * cc.wy + lx1 * cc.wy2;
    }

    f32x4 r0, r1;
    #pragma unroll
    for (int c = 0; c < 4; ++c) r0[c] = ly_a[c] * cc.wz + ly_b[c] * cc.wz2;
    #pragma unroll
    for (int c = 0; c < 4; ++c) r1[c] = ly_a[c+4] * cc.wz + ly_b[c+4] * cc.wz2;

    // out row j, cols b*8..b*8+7; scattered 32 B store — non-temporal.
    float* dst = out + (long)j * 32 + b * 8;
    __builtin_nontemporal_store(r0, reinterpret_cast<f32x4*>(dst));
    __builtin_nontemporal_store(r1, reinterpret_cast<f32x4*>(dst + 4));
}

// --------------------------- fallback --------------------------------------
__global__ __launch_bounds__(256) void og_proj_direct(
    const float* __restrict__ img, const float* __restrict__ gf,
    const int* __restrict__ dimp, float* __restrict__ out)
{
    int o = blockIdx.x * 256 + threadIdx.x;
    if (o >= TOTAL_OUT) return;
    int j = o >> 5, bc = o & 31, b = bc >> 3, c = bc & 7;
    float factor = load_image_dim(dimp) / (float)H;
    long p = (long)b * NPER + j;
    Coord cc = coord_from_xyz(gf[p*3], gf[p*3+1], gf[p*3+2], factor);

    const float* base = img + (size_t)(b * C + c) * (size_t)HWD;
    size_t r11 = ((size_t)cc.x1 * W + cc.y1) * Dd;
    size_t r12 = ((size_t)cc.x1 * W + cc.y2) * Dd;
    size_t r21 = ((size_t)cc.x2 * W + cc.y1) * Dd;
    size_t r22 = ((size_t)cc.x2 * W + cc.y2) * Dd;

    float lx1_a = base[r21 + cc.z2] * cc.wx + base[r11 + cc.z2] * cc.wx2;
    float lx2_a = base[r22 + cc.z2] * cc.wx + base[r12 + cc.z2] * cc.wx2;
    float ly_a  = lx2_a * cc.wy + lx1_a * cc.wy2;
    float lx1_b = base[r21 + cc.z1] * cc.wx + base[r11 + cc.z1] * cc.wx2;
    float lx2_b = base[r22 + cc.z1] * cc.wx + base[r12 + cc.z1] * cc.wx2;
    float ly_b  = lx2_b * cc.wy + lx1_b * cc.wy2;
    out[o] = ly_a * cc.wz + ly_b * cc.wz2;
}

extern "C" void kernel_launch(void* const* d_in, const int* in_sizes, int n_in,
                              void* d_out, int out_size, void* d_ws, size_t ws_size,
                              hipStream_t stream) {
    const float* img  = (const float*)d_in[0];
    const float* gf   = (const float*)d_in[1];
    const int*   dimp = (const int*)d_in[3];
    float* out = (float*)d_out;

    if (ws_size >= WS_NEEDED) {
        __half* ws   = (__half*)d_ws;
        int* counts  = (int*)((char*)d_ws + WS_COUNTS_OFF);
        int* parts   = (int*)((char*)d_ws + WS_PART_OFF);
        f32x4* payld = (f32x4*)((char*)d_ws + WS_PAY_OFF);

        int pblocks = (TOTAL_PTS + 255) / 256;       // 1563
        zero_kernel<<<SCAN_BLOCKS, 256, 0, stream>>>(counts);
        hist_kernel<<<pblocks, 256, 0, stream>>>(gf, dimp, counts);
        scanA_kernel<<<SCAN_BLOCKS, 256, 0, stream>>>(counts, parts);
        scanB_kernel<<<1, 512, 0, stream>>>(parts);
        scanC_kernel<<<SCAN_BLOCKS, 256, 0, stream>>>(counts, parts);
        scatter_kernel<<<pblocks, 256, 0, stream>>>(gf, dimp, counts, payld);

        long nquads = (long)B * HWD / 4;
        int tblocks = (int)((nquads + 255) / 256);   // 16,000
        transpose_kernel<<<tblocks, 256, 0, stream>>>(img, ws);
        gather_kernel<<<pblocks, 256, 0, stream>>>(ws, payld, dimp, out);
    } else {
        int blocks = (TOTAL_OUT + 255) / 256;
        og_proj_direct<<<blocks, 256, 0, stream>>>(img, gf, dimp, out);
    }
}

// Round 5
// 197.714 us; speedup vs baseline: 1.5312x; 1.1652x over previous
//
#include <hip/hip_runtime.h>

// Problem constants (match reference setup_inputs()).
constexpr int B = 4, C = 8, H = 160, W = 160, Dd = 160, NPER = 100000;
constexpr long HWD = (long)H * W * Dd;            // 4,096,000 voxels per image
constexpr int  TOTAL_PTS = NPER * B;              // 400,000 (point, image) pairs
constexpr int  TOTAL_OUT = NPER * B * C;          // 3,200,000 output elements
constexpr int  NKEYS = B * H * W;                 // 102,400 (b, x1, y1) buckets
constexpr int  SCAN_BLOCKS = NKEYS / 256;         // 400

typedef float f32x4 __attribute__((ext_vector_type(4)));

// Workspace layout (bytes) — only sort scratch now (~7 MB).
constexpr size_t WS_COUNTS_OFF = 0;
constexpr size_t WS_PART_OFF   = (size_t)NKEYS * 4;          // 409,600
constexpr size_t WS_PAY_OFF    = WS_PART_OFF + 4096;         // 16B-aligned
constexpr size_t WS_NEEDED     = WS_PAY_OFF + (size_t)TOTAL_PTS * 16;

__device__ __forceinline__ float load_image_dim(const int* dimp) {
    int iv = dimp[0];
    return (iv > 0 && iv < 1000000) ? (float)iv : __int_as_float(iv);
}

struct Coord {
    int x1, x2, y1, y2, z1, z2;
    float wx, wx2, wy, wy2, wz, wz2;
};
// Must be bit-identical in hist / scatter / gather.
__device__ __forceinline__ Coord coord_from_xyz(float gx, float gy, float gz,
                                                float factor) {
    Coord c;
    float x = gx / factor, y = gy / factor, z = gz / factor;
    float x1f = fminf(floorf(x), (float)(H - 1));
    float x2f = fminf(ceilf(x),  (float)(H - 1));
    float y1f = fminf(floorf(y), (float)(W - 1));
    float y2f = fminf(ceilf(y),  (float)(W - 1));
    float z1f = fminf(floorf(z), (float)(Dd - 1));
    float z2f = fminf(ceilf(z),  (float)(Dd - 1));
    c.x1 = max(0, (int)x1f); c.x2 = max(0, (int)x2f);
    c.y1 = max(0, (int)y1f); c.y2 = max(0, (int)y2f);
    c.z1 = max(0, (int)z1f); c.z2 = max(0, (int)z2f);
    c.wx = x - x1f; c.wx2 = x2f - x;
    c.wy = y - y1f; c.wy2 = y2f - y;
    c.wz = z - z1f; c.wz2 = z2f - z;
    return c;
}

// --------------------------- sort machinery --------------------------------
__global__ __launch_bounds__(256) void zero_kernel(int* __restrict__ counts) {
    int i = blockIdx.x * 256 + threadIdx.x;
    if (i < NKEYS) counts[i] = 0;
}

__global__ __launch_bounds__(256) void hist_kernel(
    const float* __restrict__ gf, const int* __restrict__ dimp,
    int* __restrict__ counts)
{
    int p = blockIdx.x * 256 + threadIdx.x;
    if (p >= TOTAL_PTS) return;
    float factor = load_image_dim(dimp) / (float)H;
    int b = p / NPER;
    Coord c = coord_from_xyz(gf[(long)p*3], gf[(long)p*3+1], gf[(long)p*3+2], factor);
    atomicAdd(&counts[(b * H + c.x1) * W + c.y1], 1);
}

__global__ __launch_bounds__(256) void scanA_kernel(
    int* __restrict__ counts, int* __restrict__ partials)
{
    __shared__ int sm[256];
    int g = blockIdx.x * 256 + threadIdx.x;
    int v = counts[g];
    sm[threadIdx.x] = v;
    __syncthreads();
    for (int off = 1; off < 256; off <<= 1) {
        int t = (threadIdx.x >= off) ? sm[threadIdx.x - off] : 0;
        __syncthreads();
        sm[threadIdx.x] += t;
        __syncthreads();
    }
    counts[g] = sm[threadIdx.x] - v;                 // exclusive within block
    if (threadIdx.x == 255) partials[blockIdx.x] = sm[255];
}

__global__ __launch_bounds__(512) void scanB_kernel(int* __restrict__ partials)
{
    __shared__ int sm[512];
    int t = threadIdx.x;
    int v = (t < SCAN_BLOCKS) ? partials[t] : 0;
    sm[t] = v;
    __syncthreads();
    for (int off = 1; off < 512; off <<= 1) {
        int u = (t >= off) ? sm[t - off] : 0;
        __syncthreads();
        sm[t] += u;
        __syncthreads();
    }
    if (t < SCAN_BLOCKS) partials[t] = sm[t] - v;    // exclusive
}

__global__ __launch_bounds__(256) void scanC_kernel(
    int* __restrict__ counts, const int* __restrict__ partials)
{
    int g = blockIdx.x * 256 + threadIdx.x;
    counts[g] += partials[blockIdx.x];
}

// Scatter payload {p_bits, gx, gy, gz} into sorted position.
__global__ __launch_bounds__(256) void scatter_kernel(
    const float* __restrict__ gf, const int* __restrict__ dimp,
    int* __restrict__ counts, f32x4* __restrict__ payload)
{
    int p = blockIdx.x * 256 + threadIdx.x;
    if (p >= TOTAL_PTS) return;
    float factor = load_image_dim(dimp) / (float)H;
    int b = p / NPER;
    float gx = gf[(long)p*3], gy = gf[(long)p*3+1], gz = gf[(long)p*3+2];
    Coord c = coord_from_xyz(gx, gy, gz, factor);
    int pos = atomicAdd(&counts[(b * H + c.x1) * W + c.y1], 1);
    f32x4 rec;
    rec.x = __int_as_float(p); rec.y = gx; rec.z = gy; rec.w = gz;
    payload[pos] = rec;
}

// --------------------------- sorted direct gather --------------------------
// One thread per (sorted point, channel). 8 scalar fp32 gathers from the
// ORIGINAL [B,C,H,W,D] tensor; sorting by (b,x1,y1) makes neighboring
// threads/waves touch the same 64 B lines close in time -> L2/L3 dedup.
__global__ __launch_bounds__(256) void gather_sorted(
    const float* __restrict__ img, const f32x4* __restrict__ payload,
    const int* __restrict__ dimp, float* __restrict__ out)
{
    // XCD-chunked bijective block swizzle: consecutive sorted ranges share an
    // XCD's L2 so line reuse across neighboring workgroups is captured.
    int nwg = gridDim.x;
    int q = nwg >> 3, r = nwg & 7;
    int xcd = blockIdx.x & 7, idx = blockIdx.x >> 3;
    int wg = (xcd < r) ? xcd * (q + 1) + idx
                       : r * (q + 1) + (xcd - r) * q + idx;
    int t = wg * 256 + threadIdx.x;
    if (t >= TOTAL_OUT) return;
    int i = t >> 3, c = t & 7;

    f32x4 rec = payload[i];            // 8 lanes share this 16 B -> broadcast
    int p = __float_as_int(rec.x);
    int b = p / NPER;
    int j = p - b * NPER;

    float factor = load_image_dim(dimp) / (float)H;
    Coord cc = coord_from_xyz(rec.y, rec.z, rec.w, factor);

    const float* base = img + (long)(b * C + c) * HWD;
    const float* r11 = base + ((long)cc.x1 * W + cc.y1) * Dd;
    const float* r12 = base + ((long)cc.x1 * W + cc.y2) * Dd;
    const float* r21 = base + ((long)cc.x2 * W + cc.y1) * Dd;
    const float* r22 = base + ((long)cc.x2 * W + cc.y2) * Dd;

    // z = z2 plane, then z = z1 plane (reference nesting, fp32 exact)
    float lx1_a = r21[cc.z2] * cc.wx + r11[cc.z2] * cc.wx2;
    float lx2_a = r22[cc.z2] * cc.wx + r12[cc.z2] * cc.wx2;
    float ly_a  = lx2_a * cc.wy + lx1_a * cc.wy2;
    float lx1_b = r21[cc.z1] * cc.wx + r11[cc.z1] * cc.wx2;
    float lx2_b = r22[cc.z1] * cc.wx + r12[cc.z1] * cc.wx2;
    float ly_b  = lx2_b * cc.wy + lx1_b * cc.wy2;
    float res = ly_a * cc.wz + ly_b * cc.wz2;

    // scattered 32 B-granule output row; NT store avoids polluting L2
    __builtin_nontemporal_store(res, out + (long)j * 32 + b * 8 + c);
}

// --------------------------- fallback (unsorted direct) --------------------
__global__ __launch_bounds__(256) void og_proj_direct(
    const float* __restrict__ img, const float* __restrict__ gf,
    const int* __restrict__ dimp, float* __restrict__ out)
{
    int o = blockIdx.x * 256 + threadIdx.x;
    if (o >= TOTAL_OUT) return;
    int j = o >> 5, bc = o & 31, b = bc >> 3, c = bc & 7;
    float factor = load_image_dim(dimp) / (float)H;
    long p = (long)b * NPER + j;
    Coord cc = coord_from_xyz(gf[p*3], gf[p*3+1], gf[p*3+2], factor);

    const float* base = img + (size_t)(b * C + c) * (size_t)HWD;
    size_t r11 = ((size_t)cc.x1 * W + cc.y1) * Dd;
    size_t r12 = ((size_t)cc.x1 * W + cc.y2) * Dd;
    size_t r21 = ((size_t)cc.x2 * W + cc.y1) * Dd;
    size_t r22 = ((size_t)cc.x2 * W + cc.y2) * Dd;

    float lx1_a = base[r21 + cc.z2] * cc.wx + base[r11 + cc.z2] * cc.wx2;
    float lx2_a = base[r22 + cc.z2] * cc.wx + base[r12 + cc.z2] * cc.wx2;
    float ly_a  = lx2_a * cc.wy + lx1_a * cc.wy2;
    float lx1_b = base[r21 + cc.z1] * cc.wx + base[r11 + cc.z1] * cc.wx2;
    float lx2_b = base[r22 + cc.z1] * cc.wx + base[r12 + cc.z1] * cc.wx2;
    float ly_b  = lx2_b * cc.wy + lx1_b * cc.wy2;
    out[o] = ly_a * cc.wz + ly_b * cc.wz2;
}

extern "C" void kernel_launch(void* const* d_in, const int* in_sizes, int n_in,
                              void* d_out, int out_size, void* d_ws, size_t ws_size,
                              hipStream_t stream) {
    const float* img  = (const float*)d_in[0];
    const float* gf   = (const float*)d_in[1];
    const int*   dimp = (const int*)d_in[3];
    float* out = (float*)d_out;

    if (ws_size >= WS_NEEDED) {
        int*   counts = (int*)((char*)d_ws + WS_COUNTS_OFF);
        int*   parts  = (int*)((char*)d_ws + WS_PART_OFF);
        f32x4* payld  = (f32x4*)((char*)d_ws + WS_PAY_OFF);

        int pblocks = (TOTAL_PTS + 255) / 256;       // 1563
        zero_kernel<<<SCAN_BLOCKS, 256, 0, stream>>>(counts);
        hist_kernel<<<pblocks, 256, 0, stream>>>(gf, dimp, counts);
        scanA_kernel<<<SCAN_BLOCKS, 256, 0, stream>>>(counts, parts);
        scanB_kernel<<<1, 512, 0, stream>>>(parts);
        scanC_kernel<<<SCAN_BLOCKS, 256, 0, stream>>>(counts, parts);
        scatter_kernel<<<pblocks, 256, 0, stream>>>(gf, dimp, counts, payld);

        int gblocks = (TOTAL_OUT + 255) / 256;       // 12,500
        gather_sorted<<<gblocks, 256, 0, stream>>>(img, payld, dimp, out);
    } else {
        int blocks = (TOTAL_OUT + 255) / 256;
        og_proj_direct<<<blocks, 256, 0, stream>>>(img, gf, dimp, out);
    }
}